// Round 12
// baseline (411.383 us; speedup 1.0000x reference)
//
#include <hip/hip_runtime.h>
#include <hip/hip_bf16.h>

typedef __attribute__((ext_vector_type(8))) short bf16x8;
typedef __attribute__((ext_vector_type(4))) float f32x4;
typedef __attribute__((ext_vector_type(8))) unsigned short u16x8;

#define ELL_W 64        // Poisson(16) in-degree: P(deg>64) ~ 1e-20
#define BSH   7         // 128 dst-nodes per bucket (exclusive per p2 block)
#define BMSK  ((1 << BSH) - 1)
#define BCAP  2432      // bucket capacity: mean 2048 + ~8.5 sigma
#define CHUNK 4096      // edges per block in p1 (LDS-histogram amortization)

// ---------------- helpers ----------------

__device__ __forceinline__ float bf2f(unsigned short u) {
    return __uint_as_float(((unsigned int)u) << 16);
}
__device__ __forceinline__ unsigned short f2bf(float f) {
    unsigned int u = __float_as_uint(f);
    unsigned int r = (u + 0x7fffu + ((u >> 16) & 1u)) >> 16;  // RNE
    return (unsigned short)r;
}
__device__ __forceinline__ int sel4(int sub, int4 v) {
    int s = (sub & 1) ? v.y : v.x;
    int t = (sub & 1) ? v.w : v.z;
    return (sub & 2) ? t : s;
}

// ---------------- setup: zero gcur + build wfrag + zero dummy rows --------

__global__ void setup_kernel(int N, int NB, int* __restrict__ gcur,
                             const float* __restrict__ W1, unsigned short* __restrict__ wfrag,
                             unsigned short* __restrict__ h1T, unsigned short* __restrict__ h2) {
    int nb2 = (NB * 16 + 255) >> 8;
    int b = blockIdx.x;
    if (b < nb2) {
        int i = b * 256 + threadIdx.x;
        if (i < NB * 16) gcur[i] = 0;
    } else if (b < nb2 + 8) {
        int t = (b - nb2) * 256 + threadIdx.x;   // 0..2047
        if (t < 2048) {
            int ln = t & 63;
            int blk = t >> 6;          // j*4 + k0
            int j = blk >> 2, k0 = blk & 3;
            int nn = ln & 15, cc = ln >> 4;
            int n = j * 16 + nn;
            unsigned short tmp[8];
#pragma unroll
            for (int i = 0; i < 8; ++i) {
                int k = k0 * 32 + cc * 8 + i;
                tmp[i] = f2bf(W1[(size_t)k * 128 + n]);
            }
            *(uint4*)&wfrag[(size_t)t * 8] = *(const uint4*)tmp;
        }
    } else {
        // dummy rows: h1T slice dummies (8 x 16) + h2 dummy (16)
        if (threadIdx.x < 128) {
            int s = threadIdx.x >> 4, f = threadIdx.x & 15;
            h1T[((size_t)s * (N + 1) + N) * 16 + f] = 0;
        }
        if (threadIdx.x < 16) h2[(size_t)N * 16 + threadIdx.x] = 0;
    }
}

// ---------------- P1: partition edges into dst-buckets ----------------

__global__ __launch_bounds__(256) void p1_partition_kernel(const int* __restrict__ ei, int E, int N, int NB,
                                                           int* __restrict__ gcur, int* __restrict__ bucket) {
    __shared__ int hist[1024];
    __shared__ int gbase[1024];
    __shared__ int cur2[1024];
    int tid = threadIdx.x;
    int c0 = blockIdx.x * CHUNK;

    for (int i = tid; i < NB; i += 256) { hist[i] = 0; cur2[i] = 0; }
    __syncthreads();

    int rec[16], bkt[16];
#pragma unroll
    for (int k = 0; k < 16; ++k) {
        int e = c0 + k * 256 + tid;
        int b = -1, r = 0;
        if (e < E) {
            int s = ei[e], d = ei[E + e];
            if ((unsigned)s < (unsigned)N && (unsigned)d < (unsigned)N) {
                b = d >> BSH;
                r = (s << BSH) | (d & BMSK);
            }
        }
        bkt[k] = b; rec[k] = r;
        if (b >= 0) atomicAdd(&hist[b], 1);
    }
    __syncthreads();

    for (int i = tid; i < NB; i += 256) {
        int c = hist[i];
        gbase[i] = (c > 0) ? atomicAdd(&gcur[i * 16], c) : 0;
    }
    __syncthreads();

#pragma unroll
    for (int k = 0; k < 16; ++k) {
        int b = bkt[k];
        if (b >= 0) {
            int r = atomicAdd(&cur2[b], 1);
            int pos = gbase[b] + r;
            if (pos < BCAP) bucket[(size_t)b * BCAP + pos] = rec[k];
        }
    }
}

// ---------------- P2: bucket -> ELL, one block per bucket (exclusive) -----

__global__ __launch_bounds__(256) void p2_ell_kernel(const int* __restrict__ bucket,
                                                     const int* __restrict__ gcur, int N,
                                                     int* __restrict__ deg, float* __restrict__ dinv,
                                                     int* __restrict__ ell) {
    __shared__ int lcur[128];
    int b = blockIdx.x;
    if (threadIdx.x < 128) lcur[threadIdx.x] = 0;
    __syncthreads();

    int cnt = gcur[b * 16]; if (cnt > BCAP) cnt = BCAP;
    const int* reg = &bucket[(size_t)b * BCAP];
    for (int k = threadIdx.x; k < cnt; k += 256) {
        int rec = reg[k];
        int s = (int)(((unsigned)rec) >> BSH);
        int dloc = rec & BMSK;
        int pos = atomicAdd(&lcur[dloc], 1);          // LDS atomic
        if (pos < ELL_W) ell[((size_t)(b << BSH) + dloc) * ELL_W + pos] = s;
    }
    __syncthreads();

    if (threadIdx.x < 128) {
        int i = (b << BSH) + threadIdx.x;
        if (i < N) {
            int d = lcur[threadIdx.x];
            deg[i] = d;
            dinv[i] = rsqrtf((float)(d + 1));         // +1 self-loop
            if (d > ELL_W) d = ELL_W;
            int d8 = (d + 7) & ~7; if (d8 > ELL_W) d8 = ELL_W;
            for (int k = d; k < d8; ++k) ell[(size_t)i * ELL_W + k] = N;
        }
    }
}

// ---------------- GEMM1 (MFMA): h1T[8][N+1][16] = sliced dinv.*(X @ W1) ----

__global__ __launch_bounds__(256) void gemm1_mfma_kernel(const float* __restrict__ X,
                                                         const unsigned short* __restrict__ wfrag,
                                                         const float* __restrict__ dinv,
                                                         unsigned short* __restrict__ H1T, int N) {
    __shared__ __align__(16) unsigned short wl[16384];   // 32 KB
    int tid = threadIdx.x;
    {
        uint4* dst = (uint4*)wl;
        const uint4* src = (const uint4*)wfrag;
        for (int idx = tid; idx < 2048; idx += 256) dst[idx] = src[idx];
    }
    __syncthreads();

    int lane = tid & 63;
    int wave = tid >> 6;
    int m0 = blockIdx.x * 128 + wave * 32;
    int mrow = lane & 15;
    int kc = lane >> 4;

    f32x4 acc[2][8];
#pragma unroll
    for (int rt = 0; rt < 2; ++rt)
#pragma unroll
        for (int j = 0; j < 8; ++j) acc[rt][j] = (f32x4)(0.f);

#pragma unroll
    for (int k0 = 0; k0 < 4; ++k0) {
        bf16x8 a[2];
#pragma unroll
        for (int rt = 0; rt < 2; ++rt) {
            int row = m0 + rt * 16 + mrow;
            bf16x8 av = (bf16x8)(short)0;
            if (row < N) {
                const float4* p = (const float4*)&X[(size_t)row * 128 + k0 * 32 + kc * 8];
                float4 v0 = p[0], v1 = p[1];
                av[0] = (short)f2bf(v0.x); av[1] = (short)f2bf(v0.y);
                av[2] = (short)f2bf(v0.z); av[3] = (short)f2bf(v0.w);
                av[4] = (short)f2bf(v1.x); av[5] = (short)f2bf(v1.y);
                av[6] = (short)f2bf(v1.z); av[7] = (short)f2bf(v1.w);
            }
            a[rt] = av;
        }
#pragma unroll
        for (int j = 0; j < 8; ++j) {
            bf16x8 b = *(const bf16x8*)&wl[((size_t)(j * 4 + k0) * 64 + lane) * 8];
            acc[0][j] = __builtin_amdgcn_mfma_f32_16x16x32_bf16(a[0], b, acc[0][j], 0, 0, 0);
            acc[1][j] = __builtin_amdgcn_mfma_f32_16x16x32_bf16(a[1], b, acc[1][j], 0, 0, 0);
        }
    }

    // C/D layout: col = lane&15, row = 4*(lane>>4) + r ; scale by dinv[row].
    // Output slice j lives at h1T[j][row][mrow].
#pragma unroll
    for (int rt = 0; rt < 2; ++rt) {
#pragma unroll
        for (int r = 0; r < 4; ++r) {
            int row = m0 + rt * 16 + 4 * kc + r;
            if (row < N) {
                float dv = dinv[row];
#pragma unroll
                for (int j = 0; j < 8; ++j) {
                    H1T[((size_t)j * (N + 1) + row) * 16 + mrow] = f2bf(dv * acc[rt][j][r]);
                }
            }
        }
    }
}

// ---------------- agg_slice: g1T[s] = relu(di*Σ h1T[s] + b1[s]) -----------
// slice = blockIdx & 7  -> pins each feature slice (3.2 MB) to one XCD's L2
// under round-robin dispatch. Wave = 1 node: lane = (edge slot es 0..7) x
// (feature pair fp 0..7); one VMEM gathers 8 rows x 32B. NT hints keep the
// ELL stream / g1 store from evicting the resident slice.

__global__ __launch_bounds__(256) void agg_slice_kernel(const unsigned short* __restrict__ H1T,
                                                        const int* __restrict__ ell,
                                                        const int* __restrict__ deg,
                                                        const float* __restrict__ dinv,
                                                        const float* __restrict__ b1,
                                                        unsigned short* __restrict__ G1T,
                                                        int N) {
    int s = blockIdx.x & 7;
    int grp = blockIdx.x >> 3;
    int lane = threadIdx.x & 63;
    int w = threadIdx.x >> 6;
    int es = lane >> 3;       // edge slot
    int fp = lane & 7;        // feature pair

    const unsigned short* Hs = H1T + (size_t)s * (N + 1) * 16;
    unsigned short* Gs = G1T + (size_t)s * N * 16;
    float bx = b1[s * 16 + 2 * fp];
    float by = b1[s * 16 + 2 * fp + 1];

    int ibase = grp * 16 + w * 4;
#pragma unroll
    for (int nn = 0; nn < 4; ++nn) {
        int i = ibase + nn;
        if (i >= N) continue;
        int d = deg[i]; if (d > ELL_W) d = ELL_W;
        int d8 = (d + 7) & ~7; if (d8 > ELL_W) d8 = ELL_W;
        float di = dinv[i];

        ushort2 hv = *(const ushort2*)&Hs[(unsigned)i * 16u + 2u * (unsigned)fp];
        float a0 = (es == 0) ? bf2f(hv.x) : 0.f;
        float a1 = (es == 0) ? bf2f(hv.y) : 0.f;

        const int* row = &ell[(size_t)i * ELL_W];
        for (int e = 0; e < d8; e += 8) {
            int idx = __builtin_nontemporal_load(&row[e + es]);
            ushort2 g = *(const ushort2*)&Hs[(unsigned)idx * 16u + 2u * (unsigned)fp];
            a0 += bf2f(g.x);
            a1 += bf2f(g.y);
        }
        a0 += __shfl_xor(a0, 8, 64);
        a0 += __shfl_xor(a0, 16, 64);
        a0 += __shfl_xor(a0, 32, 64);
        a1 += __shfl_xor(a1, 8, 64);
        a1 += __shfl_xor(a1, 16, 64);
        a1 += __shfl_xor(a1, 32, 64);

        if (es == 0) {
            unsigned short ox = f2bf(fmaxf(di * a0 + bx, 0.f));
            unsigned short oy = f2bf(fmaxf(di * a1 + by, 0.f));
            unsigned int packed = (unsigned int)ox | ((unsigned int)oy << 16);
            __builtin_nontemporal_store(packed, (unsigned int*)&Gs[(unsigned)i * 16u + 2u * (unsigned)fp]);
        }
    }
}

// ---------------- gemm2: h2'[N,16](bf16) = dinv .* (g1 @ W2) --------------
// Block = 64 nodes; thread (r = tid>>2, cg = tid&3) computes 4 outputs.
// g1 row read directly from the 8 slice chunks (coalesced 32B per slice).

__global__ __launch_bounds__(256) void gemm2_kernel(const unsigned short* __restrict__ G1T,
                                                    const float* __restrict__ W2,
                                                    const float* __restrict__ dinv,
                                                    unsigned short* __restrict__ h2out, int N) {
    __shared__ float W2l[128][16];
    int tid = threadIdx.x;
    for (int idx = tid; idx < 2048; idx += 256) W2l[idx >> 4][idx & 15] = W2[idx];
    __syncthreads();

    int r = tid >> 2;
    int cg = tid & 3;
    int i = blockIdx.x * 64 + r;
    if (i >= N) return;

    u16x8 xr[16];   // the node's 128 bf16 features
#pragma unroll
    for (int s = 0; s < 8; ++s) {
        const uint4* p = (const uint4*)&G1T[((size_t)s * N + i) * 16];
        *(uint4*)&xr[s * 2] = p[0];
        *(uint4*)&xr[s * 2 + 1] = p[1];
    }
    float di = dinv[i];

    float a0 = 0.f, a1 = 0.f, a2 = 0.f, a3 = 0.f;
    const unsigned short* xs = (const unsigned short*)xr;
#pragma unroll
    for (int k = 0; k < 128; ++k) {
        float xv = bf2f(xs[k]);
        float4 wv = *(const float4*)&W2l[k][cg * 4];
        a0 += xv * wv.x; a1 += xv * wv.y; a2 += xv * wv.z; a3 += xv * wv.w;
    }
    unsigned short o[4] = { f2bf(di * a0), f2bf(di * a1), f2bf(di * a2), f2bf(di * a3) };
    *(uint2*)&h2out[(size_t)i * 16 + cg * 4] = *(const uint2*)o;
}

// ---------------- agg16: out = di*(Σ h2' + h2'[i]) + b2 (fp32 out) --------

__global__ __launch_bounds__(256) void agg16_kernel(const unsigned short* __restrict__ H,
                                                    const int* __restrict__ ell,
                                                    const int* __restrict__ deg,
                                                    const float* __restrict__ dinv,
                                                    const float* __restrict__ b2,
                                                    float* __restrict__ out, int N) {
    int lane = threadIdx.x & 63;
    int i = blockIdx.x * 4 + (threadIdx.x >> 6);
    if (i >= N) return;
    int fl = lane & 7;
    int sub = lane >> 3;

    int d = deg[i]; if (d > ELL_W) d = ELL_W;
    int d8 = (d + 7) & ~7; if (d8 > ELL_W) d8 = ELL_W;
    float di = dinv[i];
    const int* row = &ell[(size_t)i * ELL_W];

    float a0, a1;
    {
        ushort2 hv = *(const ushort2*)&H[(size_t)i * 16 + 2 * fl];
        bool z = (sub != 0);
        a0 = z ? 0.f : bf2f(hv.x);
        a1 = z ? 0.f : bf2f(hv.y);
    }

    for (int e = 0; e < d8; e += 8) {
        int s = row[e + sub];
        ushort2 g = *(const ushort2*)&H[(size_t)s * 16 + 2 * fl];
        a0 += bf2f(g.x);
        a1 += bf2f(g.y);
    }

    a0 += __shfl_xor(a0, 32, 64); a0 += __shfl_xor(a0, 16, 64); a0 += __shfl_xor(a0, 8, 64);
    a1 += __shfl_xor(a1, 32, 64); a1 += __shfl_xor(a1, 16, 64); a1 += __shfl_xor(a1, 8, 64);

    if (lane < 8) {
        float2 o;
        o.x = di * a0 + b2[2 * fl];
        o.y = di * a1 + b2[2 * fl + 1];
        *(float2*)&out[(size_t)i * 16 + 2 * fl] = o;
    }
}

// ---------------- Launch ----------------

extern "C" void kernel_launch(void* const* d_in, const int* in_sizes, int n_in,
                              void* d_out, int out_size, void* d_ws, size_t ws_size,
                              hipStream_t stream) {
    const float* x = (const float*)d_in[0];
    const int* ei = (const int*)d_in[1];
    const float* W1 = (const float*)d_in[2];
    const float* b1 = (const float*)d_in[3];
    const float* W2 = (const float*)d_in[4];
    const float* b2 = (const float*)d_in[5];
    float* out = (float*)d_out;

    const int N = in_sizes[0] / 128;   // 100000
    const int E = in_sizes[1] / 2;     // 1600000
    const int NB = (N + BMSK) >> BSH;  // 782 buckets

    char* base = (char*)d_ws;
    size_t off = 0;
    auto align_up = [](size_t v) { return (v + 255) & ~(size_t)255; };

    int* deg = (int*)(base + off);                         off = align_up(off + (size_t)N * 4);
    float* dinv = (float*)(base + off);                    off = align_up(off + (size_t)N * 4);
    int* ell = (int*)(base + off);                         off = align_up(off + (size_t)N * ELL_W * 4);
    int* gcur = (int*)(base + off);                        off = align_up(off + (size_t)NB * 16 * 4);
    int* bucket = (int*)(base + off);                      off = align_up(off + (size_t)NB * BCAP * 4);
    unsigned short* wfrag = (unsigned short*)(base + off); off = align_up(off + (size_t)16384 * 2);
    unsigned short* h1T = (unsigned short*)(base + off);   off = align_up(off + (size_t)8 * (N + 1) * 16 * 2);
    unsigned short* g1T = (unsigned short*)(base + off);   off = align_up(off + (size_t)8 * N * 16 * 2);
    unsigned short* h2 = (unsigned short*)(base + off);    off = align_up(off + (size_t)(N + 1) * 16 * 2);

    int nb2 = (NB * 16 + 255) >> 8;
    setup_kernel<<<nb2 + 9, 256, 0, stream>>>(N, NB, gcur, W1, wfrag, h1T, h2);

    int nchunks = (E + CHUNK - 1) / CHUNK;
    p1_partition_kernel<<<nchunks, 256, 0, stream>>>(ei, E, N, NB, gcur, bucket);
    p2_ell_kernel<<<NB, 256, 0, stream>>>(bucket, gcur, N, deg, dinv, ell);

    gemm1_mfma_kernel<<<(N + 127) / 128, 256, 0, stream>>>(x, wfrag, dinv, h1T, N);

    int ngrp = (N + 15) / 16;
    agg_slice_kernel<<<ngrp * 8, 256, 0, stream>>>(h1T, ell, deg, dinv, b1, g1T, N);
    gemm2_kernel<<<(N + 63) / 64, 256, 0, stream>>>(g1T, W2, dinv, h2, N);
    agg16_kernel<<<(N + 3) / 4, 256, 0, stream>>>(h2, ell, deg, dinv, b2, out, N);
}

// Round 13
// 188.563 us; speedup vs baseline: 2.1817x; 2.1817x over previous
//
#include <hip/hip_runtime.h>
#include <hip/hip_bf16.h>

typedef __attribute__((ext_vector_type(8))) short bf16x8;
typedef __attribute__((ext_vector_type(4))) float f32x4;
typedef __attribute__((ext_vector_type(8))) unsigned short u16x8;

#define ELL_W 64        // Poisson(16) in-degree: P(deg>64) ~ 1e-20
#define BSH   7         // 128 dst-nodes per bucket (exclusive per p2 block)
#define BMSK  ((1 << BSH) - 1)
#define BCAP  2432      // bucket capacity: mean 2048 + ~8.5 sigma
#define CHUNK 4096      // edges per block in p1 (LDS-histogram amortization)

// ---------------- helpers ----------------

__device__ __forceinline__ float bf2f(unsigned short u) {
    return __uint_as_float(((unsigned int)u) << 16);
}
__device__ __forceinline__ unsigned short f2bf(float f) {
    unsigned int u = __float_as_uint(f);
    unsigned int r = (u + 0x7fffu + ((u >> 16) & 1u)) >> 16;  // RNE
    return (unsigned short)r;
}
__device__ __forceinline__ int sel4(int sub, int4 v) {
    int s = (sub & 1) ? v.y : v.x;
    int t = (sub & 1) ? v.w : v.z;
    return (sub & 2) ? t : s;
}

// ---------------- setup: zero gcur + build wfrag + zero dummy rows --------
// B-frag for mfma_f32_16x16x32_bf16: lane (nn=lane&15 -> n, cc=lane>>4),
// k = k0*32 + cc*8 + i. flat[((j*4+k0)*64 + lane)*8 + i], j = n-tile.

__global__ void setup_kernel(int N, int NB, int* __restrict__ gcur,
                             const float* __restrict__ W1, unsigned short* __restrict__ wfrag,
                             unsigned short* __restrict__ h1, unsigned short* __restrict__ h2) {
    int nb2 = (NB * 16 + 255) >> 8;
    int b = blockIdx.x;
    if (b < nb2) {
        int i = b * 256 + threadIdx.x;
        if (i < NB * 16) gcur[i] = 0;
    } else if (b < nb2 + 8) {
        int t = (b - nb2) * 256 + threadIdx.x;   // 0..2047
        if (t < 2048) {
            int ln = t & 63;
            int blk = t >> 6;          // j*4 + k0
            int j = blk >> 2, k0 = blk & 3;
            int nn = ln & 15, cc = ln >> 4;
            int n = j * 16 + nn;
            unsigned short tmp[8];
#pragma unroll
            for (int i = 0; i < 8; ++i) {
                int k = k0 * 32 + cc * 8 + i;
                tmp[i] = f2bf(W1[(size_t)k * 128 + n]);
            }
            *(uint4*)&wfrag[(size_t)t * 8] = *(const uint4*)tmp;
        }
    } else {
        if (threadIdx.x < 128) h1[(size_t)N * 128 + threadIdx.x] = 0;
        if (threadIdx.x < 16) h2[(size_t)N * 16 + threadIdx.x] = 0;
    }
}

// ---------------- P1: partition edges into dst-buckets ----------------
// Single LDS-atomic pass: the histogram atomicAdd's RETURN VALUE is the
// local rank (rnk). Reserve global ranges once per touched bucket, then
// write at gbase[b] + rnk. (Old version recomputed rank with a 2nd pass.)

__global__ __launch_bounds__(256) void p1_partition_kernel(const int* __restrict__ ei, int E, int N, int NB,
                                                           int* __restrict__ gcur, int* __restrict__ bucket) {
    __shared__ int hist[1024];
    __shared__ int gbase[1024];
    int tid = threadIdx.x;
    int c0 = blockIdx.x * CHUNK;

    for (int i = tid; i < NB; i += 256) hist[i] = 0;
    __syncthreads();

    int rec[16], bkt[16], rnk[16];
#pragma unroll
    for (int k = 0; k < 16; ++k) {
        int e = c0 + k * 256 + tid;
        int b = -1, r = 0, rk = 0;
        if (e < E) {
            int s = ei[e], d = ei[E + e];
            if ((unsigned)s < (unsigned)N && (unsigned)d < (unsigned)N) {
                b = d >> BSH;
                r = (s << BSH) | (d & BMSK);
            }
        }
        if (b >= 0) rk = atomicAdd(&hist[b], 1);
        bkt[k] = b; rec[k] = r; rnk[k] = rk;
    }
    __syncthreads();

    for (int i = tid; i < NB; i += 256) {
        int c = hist[i];
        gbase[i] = (c > 0) ? atomicAdd(&gcur[i * 16], c) : 0;
    }
    __syncthreads();

#pragma unroll
    for (int k = 0; k < 16; ++k) {
        int b = bkt[k];
        if (b >= 0) {
            int pos = gbase[b] + rnk[k];
            if (pos < BCAP) bucket[(size_t)b * BCAP + pos] = rec[k];
        }
    }
}

// ---------------- P2: bucket -> ELL, one block per bucket (exclusive) -----
// LDS cursors replace global atomics; epilogue writes deg, dinv, padding.

__global__ __launch_bounds__(256) void p2_ell_kernel(const int* __restrict__ bucket,
                                                     const int* __restrict__ gcur, int N,
                                                     int* __restrict__ deg, float* __restrict__ dinv,
                                                     int* __restrict__ ell) {
    __shared__ int lcur[128];
    int b = blockIdx.x;
    if (threadIdx.x < 128) lcur[threadIdx.x] = 0;
    __syncthreads();

    int cnt = gcur[b * 16]; if (cnt > BCAP) cnt = BCAP;
    const int* reg = &bucket[(size_t)b * BCAP];
    for (int k = threadIdx.x; k < cnt; k += 256) {
        int rec = reg[k];
        int s = (int)(((unsigned)rec) >> BSH);
        int dloc = rec & BMSK;
        int pos = atomicAdd(&lcur[dloc], 1);          // LDS atomic
        if (pos < ELL_W) ell[((size_t)(b << BSH) + dloc) * ELL_W + pos] = s;
    }
    __syncthreads();

    if (threadIdx.x < 128) {
        int i = (b << BSH) + threadIdx.x;
        if (i < N) {
            int d = lcur[threadIdx.x];
            deg[i] = d;
            dinv[i] = rsqrtf((float)(d + 1));         // +1 self-loop
            if (d > ELL_W) d = ELL_W;
            int d8 = (d + 7) & ~7; if (d8 > ELL_W) d8 = ELL_W;
            for (int k = d; k < d8; ++k) ell[(size_t)i * ELL_W + k] = N;
        }
    }
}

// ---------------- GEMM1 (MFMA): h1'[N,128](bf16) = dinv .* (bf16(X) @ W1) --

__global__ __launch_bounds__(256) void gemm1_mfma_kernel(const float* __restrict__ X,
                                                         const unsigned short* __restrict__ wfrag,
                                                         const float* __restrict__ dinv,
                                                         unsigned short* __restrict__ H, int N) {
    __shared__ __align__(16) unsigned short wl[16384];   // 32 KB
    int tid = threadIdx.x;
    {
        uint4* dst = (uint4*)wl;
        const uint4* src = (const uint4*)wfrag;
        for (int idx = tid; idx < 2048; idx += 256) dst[idx] = src[idx];
    }
    __syncthreads();

    int lane = tid & 63;
    int wave = tid >> 6;
    int m0 = blockIdx.x * 128 + wave * 32;
    int mrow = lane & 15;
    int kc = lane >> 4;

    f32x4 acc[2][8];
#pragma unroll
    for (int rt = 0; rt < 2; ++rt)
#pragma unroll
        for (int j = 0; j < 8; ++j) acc[rt][j] = (f32x4)(0.f);

#pragma unroll
    for (int k0 = 0; k0 < 4; ++k0) {
        bf16x8 a[2];
#pragma unroll
        for (int rt = 0; rt < 2; ++rt) {
            int row = m0 + rt * 16 + mrow;
            bf16x8 av = (bf16x8)(short)0;
            if (row < N) {
                const float4* p = (const float4*)&X[(size_t)row * 128 + k0 * 32 + kc * 8];
                float4 v0 = p[0], v1 = p[1];
                av[0] = (short)f2bf(v0.x); av[1] = (short)f2bf(v0.y);
                av[2] = (short)f2bf(v0.z); av[3] = (short)f2bf(v0.w);
                av[4] = (short)f2bf(v1.x); av[5] = (short)f2bf(v1.y);
                av[6] = (short)f2bf(v1.z); av[7] = (short)f2bf(v1.w);
            }
            a[rt] = av;
        }
#pragma unroll
        for (int j = 0; j < 8; ++j) {
            bf16x8 b = *(const bf16x8*)&wl[((size_t)(j * 4 + k0) * 64 + lane) * 8];
            acc[0][j] = __builtin_amdgcn_mfma_f32_16x16x32_bf16(a[0], b, acc[0][j], 0, 0, 0);
            acc[1][j] = __builtin_amdgcn_mfma_f32_16x16x32_bf16(a[1], b, acc[1][j], 0, 0, 0);
        }
    }

    // C/D layout: col = lane&15, row = 4*(lane>>4) + r ; scale by dinv[row]
#pragma unroll
    for (int rt = 0; rt < 2; ++rt) {
#pragma unroll
        for (int r = 0; r < 4; ++r) {
            int row = m0 + rt * 16 + 4 * kc + r;
            if (row < N) {
                float dv = dinv[row];
#pragma unroll
                for (int j = 0; j < 8; ++j) {
                    H[(size_t)row * 128 + j * 16 + mrow] = f2bf(dv * acc[rt][j][r]);
                }
            }
        }
    }
}

// ---------------- Fused: g1 = relu(di*Σh1' + b1); h2' = di*(g1 @ W2) -------
// Wave = 4 nodes (W2 regs amortized). Quad-gather: sub=lane>>4 picks edge
// e+sub, fl=lane&15 owns feats 8fl..8fl+7 (ushort8 = 16B/lane): ONE VMEM
// fetches 4 rows (1KB). ELL padded to x8 (dummy row N = zeros, L1-hot).

__global__ __launch_bounds__(256) void agg128_fused_kernel(const unsigned short* __restrict__ H,
                                                           const int* __restrict__ ell,
                                                           const int* __restrict__ deg,
                                                           const float* __restrict__ dinv,
                                                           const float* __restrict__ b1,
                                                           const float* __restrict__ W2,
                                                           unsigned short* __restrict__ h2out, int N) {
    __shared__ float gbuf[4][128];
    int lane = threadIdx.x & 63;
    int w = threadIdx.x >> 6;
    int i0 = blockIdx.x * 16 + w * 4;

    int n = lane & 15;
    int q = lane >> 4;
    int sub = lane >> 4;      // edge slot within quad
    int fl = lane & 15;       // feature group: 8fl..8fl+7

    float w2r[32];
#pragma unroll
    for (int m = 0; m < 32; ++m) {
        int mm = (m + 8 * q) & 31;                 // runtime address, constant reg index
        w2r[m] = W2[(size_t)(q * 32 + mm) * 16 + n];
    }

    for (int nn = 0; nn < 4; ++nn) {
        int i = i0 + nn;
        if (i >= N) break;
        int d = deg[i]; if (d > ELL_W) d = ELL_W;
        int d8 = (d + 7) & ~7; if (d8 > ELL_W) d8 = ELL_W;
        float di = dinv[i];

        float a0, a1, a2, a3, a4, a5, a6, a7;
        {   // self term counted once (sub==0 slot)
            u16x8 hv = *(const u16x8*)&H[(size_t)i * 128 + 8 * fl];
            bool z = (sub != 0);
            a0 = z ? 0.f : bf2f(hv[0]); a1 = z ? 0.f : bf2f(hv[1]);
            a2 = z ? 0.f : bf2f(hv[2]); a3 = z ? 0.f : bf2f(hv[3]);
            a4 = z ? 0.f : bf2f(hv[4]); a5 = z ? 0.f : bf2f(hv[5]);
            a6 = z ? 0.f : bf2f(hv[6]); a7 = z ? 0.f : bf2f(hv[7]);
        }

        const int* row = &ell[(size_t)i * ELL_W];
        for (int e = 0; e < d8; e += 8) {
            int4 svA = *(const int4*)&row[e];
            int4 svB = *(const int4*)&row[e + 4];
            int sA = sel4(sub, svA);
            int sB = sel4(sub, svB);
            u16x8 gA = *(const u16x8*)&H[(size_t)sA * 128 + 8 * fl];
            u16x8 gB = *(const u16x8*)&H[(size_t)sB * 128 + 8 * fl];
            a0 += bf2f(gA[0]) + bf2f(gB[0]);
            a1 += bf2f(gA[1]) + bf2f(gB[1]);
            a2 += bf2f(gA[2]) + bf2f(gB[2]);
            a3 += bf2f(gA[3]) + bf2f(gB[3]);
            a4 += bf2f(gA[4]) + bf2f(gB[4]);
            a5 += bf2f(gA[5]) + bf2f(gB[5]);
            a6 += bf2f(gA[6]) + bf2f(gB[6]);
            a7 += bf2f(gA[7]) + bf2f(gB[7]);
        }

        // combine the 4 sub-group partials (lane bits 4,5)
        a0 += __shfl_xor(a0, 32, 64); a0 += __shfl_xor(a0, 16, 64);
        a1 += __shfl_xor(a1, 32, 64); a1 += __shfl_xor(a1, 16, 64);
        a2 += __shfl_xor(a2, 32, 64); a2 += __shfl_xor(a2, 16, 64);
        a3 += __shfl_xor(a3, 32, 64); a3 += __shfl_xor(a3, 16, 64);
        a4 += __shfl_xor(a4, 32, 64); a4 += __shfl_xor(a4, 16, 64);
        a5 += __shfl_xor(a5, 32, 64); a5 += __shfl_xor(a5, 16, 64);
        a6 += __shfl_xor(a6, 32, 64); a6 += __shfl_xor(a6, 16, 64);
        a7 += __shfl_xor(a7, 32, 64); a7 += __shfl_xor(a7, 16, 64);

        if (sub == 0) {
            float4 bb0 = *(const float4*)&b1[8 * fl];
            float4 bb1 = *(const float4*)&b1[8 * fl + 4];
            float4 g0, g1;
            g0.x = fmaxf(di * a0 + bb0.x, 0.f);
            g0.y = fmaxf(di * a1 + bb0.y, 0.f);
            g0.z = fmaxf(di * a2 + bb0.z, 0.f);
            g0.w = fmaxf(di * a3 + bb0.w, 0.f);
            g1.x = fmaxf(di * a4 + bb1.x, 0.f);
            g1.y = fmaxf(di * a5 + bb1.y, 0.f);
            g1.z = fmaxf(di * a6 + bb1.z, 0.f);
            g1.w = fmaxf(di * a7 + bb1.w, 0.f);
            *(float4*)&gbuf[w][8 * fl] = g0;
            *(float4*)&gbuf[w][8 * fl + 4] = g1;
        }
        asm volatile("s_waitcnt lgkmcnt(0)" ::: "memory");   // wave-internal LDS RAW

        float partial = 0.f;
#pragma unroll
        for (int t = 0; t < 8; ++t) {
            int off = (t * 4 + 8 * q) & 31;                  // staggered: conflict-free
            float4 gv = *(const float4*)&gbuf[w][q * 32 + off];
            partial += gv.x * w2r[t * 4 + 0] + gv.y * w2r[t * 4 + 1] +
                       gv.z * w2r[t * 4 + 2] + gv.w * w2r[t * 4 + 3];
        }
        partial += __shfl_xor(partial, 16, 64);
        partial += __shfl_xor(partial, 32, 64);
        // store h2' = dinv[i] * h2[i]
        if (lane < 16) h2out[(size_t)i * 16 + lane] = f2bf(di * partial);
    }
}

// ---------------- agg16: out = di*(Σ h2' + h2'[i]) + b2 (fp32 out) --------
// One wave per node; oct-gather: sub=lane>>3 picks edge e+sub, fl=lane&7
// owns feats 2fl,2fl+1 (ushort2): ONE VMEM fetches 8 rows (256B).

__global__ __launch_bounds__(256) void agg16_kernel(const unsigned short* __restrict__ H,
                                                    const int* __restrict__ ell,
                                                    const int* __restrict__ deg,
                                                    const float* __restrict__ dinv,
                                                    const float* __restrict__ b2,
                                                    float* __restrict__ out, int N) {
    int lane = threadIdx.x & 63;
    int i = blockIdx.x * 4 + (threadIdx.x >> 6);
    if (i >= N) return;
    int fl = lane & 7;
    int sub = lane >> 3;

    int d = deg[i]; if (d > ELL_W) d = ELL_W;
    int d8 = (d + 7) & ~7; if (d8 > ELL_W) d8 = ELL_W;
    float di = dinv[i];
    const int* row = &ell[(size_t)i * ELL_W];

    float a0, a1;
    {
        ushort2 hv = *(const ushort2*)&H[(size_t)i * 16 + 2 * fl];
        bool z = (sub != 0);
        a0 = z ? 0.f : bf2f(hv.x);
        a1 = z ? 0.f : bf2f(hv.y);
    }

    for (int e = 0; e < d8; e += 8) {
        int s = row[e + sub];
        ushort2 g = *(const ushort2*)&H[(size_t)s * 16 + 2 * fl];
        a0 += bf2f(g.x);
        a1 += bf2f(g.y);
    }

    a0 += __shfl_xor(a0, 32, 64); a0 += __shfl_xor(a0, 16, 64); a0 += __shfl_xor(a0, 8, 64);
    a1 += __shfl_xor(a1, 32, 64); a1 += __shfl_xor(a1, 16, 64); a1 += __shfl_xor(a1, 8, 64);

    if (lane < 8) {
        float2 o;
        o.x = di * a0 + b2[2 * fl];
        o.y = di * a1 + b2[2 * fl + 1];
        *(float2*)&out[(size_t)i * 16 + 2 * fl] = o;
    }
}

// ---------------- Launch ----------------

extern "C" void kernel_launch(void* const* d_in, const int* in_sizes, int n_in,
                              void* d_out, int out_size, void* d_ws, size_t ws_size,
                              hipStream_t stream) {
    const float* x = (const float*)d_in[0];
    const int* ei = (const int*)d_in[1];
    const float* W1 = (const float*)d_in[2];
    const float* b1 = (const float*)d_in[3];
    const float* W2 = (const float*)d_in[4];
    const float* b2 = (const float*)d_in[5];
    float* out = (float*)d_out;

    const int N = in_sizes[0] / 128;   // 100000
    const int E = in_sizes[1] / 2;     // 1600000
    const int NB = (N + BMSK) >> BSH;  // 782 buckets

    char* base = (char*)d_ws;
    size_t off = 0;
    auto align_up = [](size_t v) { return (v + 255) & ~(size_t)255; };

    int* deg = (int*)(base + off);                         off = align_up(off + (size_t)N * 4);
    float* dinv = (float*)(base + off);                    off = align_up(off + (size_t)N * 4);
    int* ell = (int*)(base + off);                         off = align_up(off + (size_t)N * ELL_W * 4);
    int* gcur = (int*)(base + off);                        off = align_up(off + (size_t)NB * 16 * 4);
    int* bucket = (int*)(base + off);                      off = align_up(off + (size_t)NB * BCAP * 4);
    unsigned short* wfrag = (unsigned short*)(base + off); off = align_up(off + (size_t)16384 * 2);
    unsigned short* h1 = (unsigned short*)(base + off);    off = align_up(off + (size_t)(N + 1) * 128 * 2);
    unsigned short* h2 = (unsigned short*)(base + off);    off = align_up(off + (size_t)(N + 1) * 16 * 2);

    int nb2 = (NB * 16 + 255) >> 8;
    setup_kernel<<<nb2 + 9, 256, 0, stream>>>(N, NB, gcur, W1, wfrag, h1, h2);

    int nchunks = (E + CHUNK - 1) / CHUNK;
    p1_partition_kernel<<<nchunks, 256, 0, stream>>>(ei, E, N, NB, gcur, bucket);
    p2_ell_kernel<<<NB, 256, 0, stream>>>(bucket, gcur, N, deg, dinv, ell);

    gemm1_mfma_kernel<<<(N + 127) / 128, 256, 0, stream>>>(x, wfrag, dinv, h1, N);
    agg128_fused_kernel<<<(N + 15) / 16, 256, 0, stream>>>(h1, ell, deg, dinv, b1, W2, h2, N);
    agg16_kernel<<<(N + 3) / 4, 256, 0, stream>>>(h2, ell, deg, dinv, b2, out, N);
}